// Round 1
// baseline (112.402 us; speedup 1.0000x reference)
//
#include <hip/hip_runtime.h>
#include <hip/hip_bf16.h>
#include <math.h>

typedef __attribute__((ext_vector_type(8))) short bf16x8;
typedef __attribute__((ext_vector_type(4))) float f32x4;

#define B_ 2
#define L_ 2048
#define S_ 2048
#define H_ 16
#define E_ 64
#define D_ 64
#define QBLK 64
#define KVBLK 32

__device__ __forceinline__ unsigned short f2bf(float x) {
  unsigned int u = __float_as_uint(x);
  u += 0x7FFFu + ((u >> 16) & 1u);   // round-to-nearest-even
  return (unsigned short)(u >> 16);
}

__device__ __forceinline__ uint4 pack8(float4 a, float4 b) {
  uint4 r;
  r.x = (unsigned)f2bf(a.x) | ((unsigned)f2bf(a.y) << 16);
  r.y = (unsigned)f2bf(a.z) | ((unsigned)f2bf(a.w) << 16);
  r.z = (unsigned)f2bf(b.x) | ((unsigned)f2bf(b.y) << 16);
  r.w = (unsigned)f2bf(b.z) | ((unsigned)f2bf(b.w) << 16);
  return r;
}

__global__ __launch_bounds__(256)
void fa_fwd_kernel(const float* __restrict__ Qp, const float* __restrict__ Kp,
                   const float* __restrict__ Vp, float* __restrict__ Op) {
  __shared__ uint4 sK[256];   // K tile: 32 rows x 128 B (bf16, swizzled)
  __shared__ uint4 sV[256];   // V^T tile: 64 rows x 64 B (bf16, swizzled)
  __shared__ uint4 sP[320];   // P: 4 waves x 16 rows x 80 B
  char* lk = (char*)sK;
  char* lv = (char*)sV;
  char* lp = (char*)sP;

  const int tid  = threadIdx.x;
  const int lane = tid & 63;
  const int w    = tid >> 6;
  const int lo   = lane & 15;
  const int hi   = lane >> 4;

  const int bid = blockIdx.x;
  const int bh  = bid & 31;           // 32 (b,h) pairs, adjacent blocks spread over bh
  const int b   = bh >> 4;
  const int h   = bh & 15;
  const int q0  = (31 - (bid >> 5)) * QBLK;  // longest blocks launch first
  const int nt  = (q0 + QBLK) / KVBLK;

  const float cs = 0.125f * 1.44269504088896f;  // scale * log2(e)

  // ---- Q fragments (A-operand), held in registers for the whole kernel ----
  bf16x8 qf[2];
  {
    const int qrow = q0 + w * 16 + lo;
    const float* gq = Qp + ((size_t)(b * L_ + qrow) * H_ + h) * E_ + hi * 8;
    #pragma unroll
    for (int kk = 0; kk < 2; ++kk) {
      float4 a = *(const float4*)(gq + kk * 32);
      float4 c = *(const float4*)(gq + kk * 32 + 4);
      uint4 pk = pack8(a, c);
      qf[kk] = *(bf16x8*)&pk;
    }
  }

  float mrun[4], lsum[4];
  f32x4 acc[4];
  #pragma unroll
  for (int r = 0; r < 4; ++r) { mrun[r] = -INFINITY; lsum[r] = 0.f; }
  #pragma unroll
  for (int n = 0; n < 4; ++n) acc[n] = (f32x4){0.f, 0.f, 0.f, 0.f};

  const int pbase = w * 16 * 80;

  for (int t = 0; t < nt; ++t) {
    const int kv0 = t * KVBLK;
    __syncthreads();  // previous tile's K/V reads complete before restage

    // ---- stage K tile: 32 x 64 f32 -> bf16 LDS (XOR-swizzled rows) ----
    {
      const int row = tid >> 3, seg = tid & 7;
      const float* gk = Kp + ((size_t)(b * S_ + kv0 + row) * H_ + h) * E_ + seg * 8;
      float4 a = *(const float4*)gk;
      float4 c = *(const float4*)(gk + 4);
      uint4 pk = pack8(a, c);
      *(uint4*)(lk + ((row * 128 + seg * 16) ^ ((row & 7) << 4))) = pk;
    }
    // ---- stage V transposed: Vt[d][kv] (coalesced global reads) ----
    {
      const int d = tid & 63, kg = tid >> 6;
      const float* gv = Vp + ((size_t)(b * S_ + kv0 + kg * 8) * H_ + h) * D_ + d;
      unsigned short vb[8];
      #pragma unroll
      for (int k = 0; k < 8; ++k) vb[k] = f2bf(gv[(size_t)k * H_ * D_]);
      uint4 pk;
      pk.x = (unsigned)vb[0] | ((unsigned)vb[1] << 16);
      pk.y = (unsigned)vb[2] | ((unsigned)vb[3] << 16);
      pk.z = (unsigned)vb[4] | ((unsigned)vb[5] << 16);
      pk.w = (unsigned)vb[6] | ((unsigned)vb[7] << 16);
      *(uint4*)(lv + ((d * 64 + kg * 16) ^ ((d & 7) << 4))) = pk;
    }
    __syncthreads();

    // ---- scores: S[16q x 32kv] = Q(16x64) . K^T(64x32) ----
    f32x4 s0 = {0.f, 0.f, 0.f, 0.f}, s1 = {0.f, 0.f, 0.f, 0.f};
    {
      const int swz = (lo & 7) << 4;
      bf16x8 k00 = *(bf16x8*)(lk + (((lo)      * 128      + hi * 16) ^ swz));
      bf16x8 k01 = *(bf16x8*)(lk + (((lo)      * 128 + 64 + hi * 16) ^ swz));
      bf16x8 k10 = *(bf16x8*)(lk + (((16 + lo) * 128      + hi * 16) ^ swz));
      bf16x8 k11 = *(bf16x8*)(lk + (((16 + lo) * 128 + 64 + hi * 16) ^ swz));
      s0 = __builtin_amdgcn_mfma_f32_16x16x32_bf16(qf[0], k00, s0, 0, 0, 0);
      s0 = __builtin_amdgcn_mfma_f32_16x16x32_bf16(qf[1], k01, s0, 0, 0, 0);
      s1 = __builtin_amdgcn_mfma_f32_16x16x32_bf16(qf[0], k10, s1, 0, 0, 0);
      s1 = __builtin_amdgcn_mfma_f32_16x16x32_bf16(qf[1], k11, s1, 0, 0, 0);
    }

    // ---- online softmax (fp32 state, per-row reduce across 16 lanes) ----
    float fac[4];
    #pragma unroll
    for (int r = 0; r < 4; ++r) {
      const int qg = q0 + w * 16 + hi * 4 + r;
      float t0 = (kv0 + lo      > qg) ? -1e30f : s0[r] * cs;
      float t1 = (kv0 + 16 + lo > qg) ? -1e30f : s1[r] * cs;
      float mx = fmaxf(t0, t1);
      mx = fmaxf(mx, __shfl_xor(mx, 1));
      mx = fmaxf(mx, __shfl_xor(mx, 2));
      mx = fmaxf(mx, __shfl_xor(mx, 4));
      mx = fmaxf(mx, __shfl_xor(mx, 8));
      const float mnew = fmaxf(mrun[r], mx);
      const float f = exp2f(mrun[r] - mnew);   // exp2(-inf)=0 on first tile
      mrun[r] = mnew;
      const float p0 = exp2f(t0 - mnew);
      const float p1 = exp2f(t1 - mnew);
      float ps = p0 + p1;
      ps += __shfl_xor(ps, 1);
      ps += __shfl_xor(ps, 2);
      ps += __shfl_xor(ps, 4);
      ps += __shfl_xor(ps, 8);
      lsum[r] = lsum[r] * f + ps;
      fac[r] = f;
      const int prow = hi * 4 + r;
      *(unsigned short*)(lp + pbase + prow * 80 +      lo * 2) = f2bf(p0);
      *(unsigned short*)(lp + pbase + prow * 80 + 32 + lo * 2) = f2bf(p1);
    }
    #pragma unroll
    for (int n = 0; n < 4; ++n)
      #pragma unroll
      for (int r = 0; r < 4; ++r) acc[n][r] *= fac[r];

    __syncthreads();  // P visible (wave-private, but conservative for round 1)

    // ---- PV: O[16q x 64d] += P(16x32) . V(32x64) ----
    bf16x8 pf = *(bf16x8*)(lp + pbase + lo * 80 + hi * 16);
    #pragma unroll
    for (int n = 0; n < 4; ++n) {
      const int vr = n * 16 + lo;
      bf16x8 vf = *(bf16x8*)(lv + ((vr * 64 + hi * 16) ^ ((lo & 7) << 4)));
      acc[n] = __builtin_amdgcn_mfma_f32_16x16x32_bf16(pf, vf, acc[n], 0, 0, 0);
    }
  }

  // ---- epilogue: O = acc / lsum ----
  #pragma unroll
  for (int r = 0; r < 4; ++r) {
    const float inv = 1.0f / lsum[r];
    const int qg = q0 + w * 16 + hi * 4 + r;
    float* go = Op + ((size_t)(b * L_ + qg) * H_ + h) * D_ + lo;
    go[0]  = acc[0][r] * inv;
    go[16] = acc[1][r] * inv;
    go[32] = acc[2][r] * inv;
    go[48] = acc[3][r] * inv;
  }
}

extern "C" void kernel_launch(void* const* d_in, const int* in_sizes, int n_in,
                              void* d_out, int out_size, void* d_ws, size_t ws_size,
                              hipStream_t stream) {
  (void)in_sizes; (void)n_in; (void)d_ws; (void)ws_size; (void)out_size;
  const float* Q = (const float*)d_in[0];
  const float* K = (const float*)d_in[1];
  const float* V = (const float*)d_in[2];
  float* O = (float*)d_out;
  dim3 grid(B_ * H_ * (L_ / QBLK));
  fa_fwd_kernel<<<grid, 256, 0, stream>>>(Q, K, V, O);
}